// Round 1
// baseline (85.824 us; speedup 1.0000x reference)
//
#include <hip/hip_runtime.h>

// Problem constants (from reference setup_inputs)
#define B_   8
#define CIN  3
#define OC   16
#define HH   128
#define WW   128
#define KK   3
#define FF   27            // CIN*KK*KK
#define NSITE (B_*HH*WW)   // 131072 output pixel-sites
#define OGRP 4             // output channels per block
#define NCOL (OGRP*FF)     // 108 staged LUT columns
#define MBLK 512           // main-kernel block size

// ---------------------------------------------------------------------------
// Prep kernel: builds (1) transposed product table T[b*256+a] = hi*256+(lo&255)
// of lut[a*256+b]  (transposed so LDS gathers on 'a' spread across banks),
// (2) qa = clip(round(x/sx)) + 128 as uint8, (3) qwb = clip(round(w/sw)) + 128.
// Quantization must be bit-exact vs numpy: IEEE f32 divide + rintf (nearest-
// even, matches np.round) + clip.
// ---------------------------------------------------------------------------
__global__ void prep_kernel(const float* __restrict__ x,
                            const float* __restrict__ wgt,
                            const float* __restrict__ sx_p,
                            const float* __restrict__ sw_p,
                            const int*   __restrict__ lut,
                            short*       __restrict__ T,
                            int*         __restrict__ qwb,
                            unsigned char* __restrict__ qa)
{
    int i = blockIdx.x * blockDim.x + threadIdx.x;

    if (i < 65536) {
        int b = i >> 8, a = i & 255;
        int r = (a << 8) | b;                 // original lut row = ip*256 + iw
        int hi = lut[2 * r];
        int lo = lut[2 * r + 1] & 255;
        T[i] = (short)(hi * 256 + lo);        // fits int16: [-32512, 32767]
    }
    if (i < B_ * CIN * HH * WW) {
        float q = rintf(x[i] / sx_p[0]);
        q = fminf(127.f, fmaxf(-127.f, q));
        qa[i] = (unsigned char)((int)q + 128);   // ip in [1,255]
    }
    if (i < OC * FF) {
        float q = rintf(wgt[i] / sw_p[0]);
        q = fminf(127.f, fmaxf(-127.f, q));
        qwb[i] = (int)q + 128;                   // iw in [1,255]
    }
}

// ---------------------------------------------------------------------------
// Main kernel: each block = (512 pixel-sites) x (4 output channels).
// Stages the 108 needed LUT columns (54 KB) into LDS with coalesced reads
// (columns are contiguous in the transposed table). Gathers are then
// ds_read_i16 with compile-time immediate column offset (j*512 <= 54784
// fits the 16-bit DS offset) — 1 DS + 1 VALU add per gather.
// 54 KB LDS -> 2 blocks/CU (16 waves/CU) for latency hiding.
// ---------------------------------------------------------------------------
__global__ __launch_bounds__(MBLK, 4) void conv_kernel(
    const unsigned char* __restrict__ qa,
    const int*   __restrict__ qwb,
    const short* __restrict__ T,
    const float* __restrict__ bias,
    const float* __restrict__ sx_p,
    const float* __restrict__ sw_p,
    float*       __restrict__ out)
{
    __shared__ short col[NCOL * 256];   // 55296 B

    const int og   = blockIdx.x & 3;    // output-channel group
    const int sblk = blockIdx.x >> 2;   // site block

    // Stage columns: col[j*256 + a] = T[qwb[o,f]*256 + a], j = ol*27 + f.
    for (int e = threadIdx.x; e < NCOL * 256; e += MBLK) {
        int j  = e >> 8;
        int a  = e & 255;
        int ol = j / FF;
        int f  = j - ol * FF;
        int o  = og * OGRP + ol;
        col[e] = T[(qwb[o * FF + f] << 8) | a];
    }
    __syncthreads();

    const int s  = sblk * MBLK + threadIdx.x;   // site id, exact grid (no bounds)
    const int b  = s >> 14;
    const int hw = s & 16383;
    const int h  = hw >> 7;
    const int w  = hw & 127;

    // Load 3x3x3 patch of quantized activations; zero-pad => qx=0 => a=128.
    int av[FF];
    #pragma unroll
    for (int c = 0; c < CIN; ++c) {
        const unsigned char* base = qa + (b * CIN + c) * (HH * WW);
        #pragma unroll
        for (int kh = 0; kh < KK; ++kh) {
            int hh2 = h + kh - 1;
            #pragma unroll
            for (int kw = 0; kw < KK; ++kw) {
                int ww2 = w + kw - 1;
                int a = 128;
                if ((unsigned)hh2 < HH && (unsigned)ww2 < WW)
                    a = base[hh2 * WW + ww2];
                av[c * 9 + kh * 3 + kw] = a;
            }
        }
    }

    const float sxw = sx_p[0] * sw_p[0];
    #pragma unroll
    for (int ol = 0; ol < OGRP; ++ol) {
        int acc = 0;
        #pragma unroll
        for (int f = 0; f < FF; ++f) {
            acc += col[(ol * FF + f) * 256 + av[f]];   // ds_read_i16, imm offset
        }
        int o = og * OGRP + ol;
        out[((b * OC + o) * HH + h) * WW + w] = (float)acc * sxw + bias[o];
    }
}

// ---------------------------------------------------------------------------
// d_in order: x, weight, bias, scale_x, scale_w, lut
// ws layout: T (131072 B) | qwb (1728 B, padded to 2048) | qa (393216 B)
//            total 526336 B
// ---------------------------------------------------------------------------
extern "C" void kernel_launch(void* const* d_in, const int* in_sizes, int n_in,
                              void* d_out, int out_size, void* d_ws, size_t ws_size,
                              hipStream_t stream)
{
    const float* x    = (const float*)d_in[0];
    const float* wgt  = (const float*)d_in[1];
    const float* bias = (const float*)d_in[2];
    const float* sx   = (const float*)d_in[3];
    const float* sw   = (const float*)d_in[4];
    const int*   lut  = (const int*)d_in[5];

    char* ws = (char*)d_ws;
    short* T           = (short*)ws;                       // 131072 B
    int* qwb           = (int*)(ws + 131072);              // 1728 B
    unsigned char* qa  = (unsigned char*)(ws + 131072 + 2048); // 393216 B

    // prep: 393216 threads covers qa (largest job); T and qwb are subsets
    prep_kernel<<<(B_ * CIN * HH * WW) / 256, 256, 0, stream>>>(
        x, wgt, sx, sw, lut, T, qwb, qa);

    // main: 256 site-blocks x 4 channel-groups = 1024 blocks
    conv_kernel<<<(NSITE / MBLK) * 4, MBLK, 0, stream>>>(
        qa, qwb, T, bias, sx, sw, (float*)d_out);
}